// Round 1
// 4701.871 us; speedup vs baseline: 3.0897x; 3.0897x over previous
//
#include <hip/hip_runtime.h>

// 6-layer GRU, T=512, B=256, I=128, H=256. ALL I/O IS FLOAT32. MFMA operands
// are converted f32->bf16 on the fly; h carried in f32; internal gx ws is bf16.
// d_out = [cur 512*256*256][finals 6*256*256] f32.
//
// THIS VERSION: wavefront pipeline across (layer, chunk). scan(l,c) depends on
// gemm(l,c) and scan(l,c-1); gemm(l,c) depends on scan(l-1,c). All pairs with
// l+c==s are independent -> per slot s launch ONE batched gx_gemm (blockIdx.z =
// pair) then ONE batched gru_scan (blockIdx.y = pair). Single-stream ordering
// supplies every dependency, including in-place chaining through d_out
// (gemm(l+1,c) reads cur chunk c at slot s+1 BEFORE scan(l+1,c) overwrites it
// in that same slot). Serial path: NLAY*512 steps -> (NLAY+nch-1)*(512/nch).
// ws = NLAY gx buffers (one per in-flight layer) + NLAY hcar carries.

#define NLAY 6

typedef __bf16 bf16x8 __attribute__((ext_vector_type(8)));
typedef float  f32x4  __attribute__((ext_vector_type(4)));

typedef const unsigned int __attribute__((address_space(1)))* gp1_t;
typedef unsigned int __attribute__((address_space(3)))* lp3_t;

__device__ __forceinline__ float b2f(unsigned short u) {
  union { unsigned int i; float f; } v; v.i = ((unsigned int)u) << 16; return v.f;
}
__device__ __forceinline__ unsigned short f2bs(float f) {
  union { __bf16 b; unsigned short s; } v; v.b = (__bf16)f; return v.s;
}
__device__ __forceinline__ bf16x8 cvt8(f32x4 lo, f32x4 hi) {
  bf16x8 r;
#pragma unroll
  for (int i = 0; i < 4; ++i) { r[i] = (__bf16)lo[i]; r[4 + i] = (__bf16)hi[i]; }
  return r;
}

struct GemmBatch {
  const float* X[NLAY];
  const float* W[NLAY];
  const float* bih[NLAY];
  const float* bhh[NLAY];
  unsigned short* GX[NLAY];
  int K[NLAY];
};

// ---------------------------------------------------------------------------
// gx[m,g] = sum_k X[m,k]*W[g,k] + bias(g);  m = t*256+b (chunk-local t)
// X: [M][K] f32 row-major, W: [768][K] f32 row-major, K in {128,256}.
// GX (bf16): (t,b,g) -> GX[((t*16 + (b>>4))*768 + g)*16 + (b&15)]
// grid = (Tc*2, 6, npairs), block = 256. LDS slabs [128 rows][32 k] f32, 8
// 16B-groups per row; physical group g holds logical group g ^ (row&7).
// ---------------------------------------------------------------------------
__global__ __launch_bounds__(256) void gx_gemm(GemmBatch args)
{
  __shared__ __align__(16) float Asf[128 * 32];
  __shared__ __align__(16) float Bsf[128 * 32];
  const int p = blockIdx.z;
  const float* __restrict__ X  = args.X[p];
  const float* __restrict__ W  = args.W[p];
  const float* __restrict__ bihp = args.bih[p];
  const float* __restrict__ bhhp = args.bhh[p];
  unsigned short* __restrict__ GX = args.GX[p];
  const int K = args.K[p];

  const int tid  = threadIdx.x;
  const int lane = tid & 63;
  const int w    = tid >> 6;           // wave 0..3
  const int wy   = w >> 1, wx = w & 1; // 2x2 wave grid, 64x64 per wave
  const int l15  = lane & 15, q = lane >> 4;
  const int m0   = blockIdx.x * 128;
  const int n0   = blockIdx.y * 128;

  f32x4 acc[4][4];
#pragma unroll
  for (int a = 0; a < 4; ++a)
#pragma unroll
    for (int b = 0; b < 4; ++b) acc[a][b] = f32x4{0.f, 0.f, 0.f, 0.f};

  const int kiters = K >> 5;
  for (int kt = 0; kt < kiters; ++kt) {
    // stage: 1024 16B-chunks per slab (128 rows x 8 groups of 4 floats)
#pragma unroll
    for (int i = 0; i < 4; ++i) {
      int ci  = (w * 4 + i) * 64 + lane;   // 0..1023
      int row = ci >> 3;
      int g   = ci & 7;
      int kg  = g ^ (row & 7);
      const float* srcA = X + (size_t)(m0 + row) * K + kt * 32 + kg * 4;
      const float* srcB = W + (size_t)(n0 + row) * K + kt * 32 + kg * 4;
      __builtin_amdgcn_global_load_lds((gp1_t)(const void*)srcA,
          (lp3_t)(void*)((char*)Asf + (w * 4 + i) * 1024), 16, 0, 0);
      __builtin_amdgcn_global_load_lds((gp1_t)(const void*)srcB,
          (lp3_t)(void*)((char*)Bsf + (w * 4 + i) * 1024), 16, 0, 0);
    }
    __syncthreads();

    bf16x8 a[4], b[4];
#pragma unroll
    for (int tm = 0; tm < 4; ++tm) {
      int row = wy * 64 + tm * 16 + l15;
      int p0  = (2 * q) ^ (row & 7);
      int p1  = (2 * q + 1) ^ (row & 7);
      f32x4 lo = *(const f32x4*)(Asf + row * 32 + p0 * 4);
      f32x4 hi = *(const f32x4*)(Asf + row * 32 + p1 * 4);
      a[tm] = cvt8(lo, hi);
    }
#pragma unroll
    for (int tn = 0; tn < 4; ++tn) {
      int row = wx * 64 + tn * 16 + l15;
      int p0  = (2 * q) ^ (row & 7);
      int p1  = (2 * q + 1) ^ (row & 7);
      f32x4 lo = *(const f32x4*)(Bsf + row * 32 + p0 * 4);
      f32x4 hi = *(const f32x4*)(Bsf + row * 32 + p1 * 4);
      b[tn] = cvt8(lo, hi);
    }
#pragma unroll
    for (int tm = 0; tm < 4; ++tm)
#pragma unroll
      for (int tn = 0; tn < 4; ++tn)
        acc[tm][tn] = __builtin_amdgcn_mfma_f32_16x16x32_bf16(a[tm], b[tn], acc[tm][tn], 0, 0, 0);
    __syncthreads();
  }

  // epilogue: bias add (+b_hh folded for gates r,z i.e. g<512), bf16, permuted
#pragma unroll
  for (int tn = 0; tn < 4; ++tn) {
    int g = n0 + wx * 64 + tn * 16 + l15;
    float bias = bihp[g] + (g < 512 ? bhhp[g] : 0.f);
#pragma unroll
    for (int tm = 0; tm < 4; ++tm) {
#pragma unroll
      for (int r = 0; r < 4; ++r) {
        int m = m0 + wy * 64 + tm * 16 + q * 4 + r;  // C row = 4*q + r
        int t = m >> 8, bb = m & 255;
        size_t dst = ((size_t)(t * 16 + (bb >> 4)) * 768 + g) * 16 + (bb & 15);
        GX[dst] = f2bs(acc[tm][tn][r] + bias);
      }
    }
  }
}

struct ScanBatch {
  const unsigned short* GX[NLAY];
  const float* Whh[NLAY];
  const float* bhh[NLAY];
  float* hcar[NLAY];
  const float* h0[NLAY];
  float* Y[NLAY];
  float* FIN[NLAY];
  int first[NLAY];
  int Tc;
};

// ---------------------------------------------------------------------------
// Recurrent scan. grid = (16, npairs): blockIdx.y selects the (layer,chunk)
// pair, blockIdx.x the 16-batch-row slice (no inter-WG comm within a pair).
// 8 waves; wave w owns gh columns [32w,32w+32) for all 3 gates (6 MFMA
// N-tiles). W_hh bf16 B-fragments resident in VGPRs. h in f32 regs (lane:
// rows 4q+r, cols jb+16c); bf16 h in double-buffered swizzled LDS (A-op).
// ---------------------------------------------------------------------------
__global__ __launch_bounds__(512, 2) void gru_scan(ScanBatch args)
{
  __shared__ __align__(16) unsigned short hl[2][16 * 256];  // bf16 h, dbuf, swizzled
  const int p = blockIdx.y;
  const unsigned short* __restrict__ GX = args.GX[p];
  const float* __restrict__ Whh = args.Whh[p];
  const float* __restrict__ bhh = args.bhh[p];
  float* __restrict__ hcar = args.hcar[p];
  const float* __restrict__ h0 = args.h0[p];
  float* __restrict__ Y = args.Y[p];
  float* __restrict__ FIN = args.FIN[p];
  const int Tc = args.Tc;
  const int first = args.first[p];

  const int wg  = blockIdx.x;
  const int b0  = wg << 4;
  const int tid = threadIdx.x;
  const int lane = tid & 63;
  const int w  = tid >> 6;       // 0..7
  const int m  = lane & 15;
  const int q  = lane >> 4;
  const int jb = w * 32 + m;     // j col base (c adds 16)

  // resident W_hh B-fragments: B[k][n], n(lane&15)=W row, k = kt*32+8q+i
  bf16x8 bw[6][8];
#pragma unroll
  for (int gate = 0; gate < 3; ++gate)
#pragma unroll
    for (int c = 0; c < 2; ++c) {
      int n = gate * 256 + jb + c * 16;
#pragma unroll
      for (int kt = 0; kt < 8; ++kt) {
        f32x4 lo = *(const f32x4*)(Whh + (size_t)n * 256 + kt * 32 + q * 8);
        f32x4 hi = *(const f32x4*)(Whh + (size_t)n * 256 + kt * 32 + q * 8 + 4);
        bw[gate * 2 + c][kt] = cvt8(lo, hi);
      }
    }

  float bhn[2];
#pragma unroll
  for (int c = 0; c < 2; ++c) bhn[c] = bhh[512 + jb + c * 16];

  // h registers: rows b0+4q+r, cols jb+16c
  float h[2][4];
#pragma unroll
  for (int c = 0; c < 2; ++c)
#pragma unroll
    for (int r = 0; r < 4; ++r) {
      int bb = b0 + q * 4 + r;
      int j  = jb + c * 16;
      h[c][r] = first ? h0[bb * 256 + j] : hcar[bb * 256 + j];
    }

  // init LDS buf 0 (swizzle: addr = b*256 + (((j>>3)^(b&7))<<3) + (j&7))
#pragma unroll
  for (int c = 0; c < 2; ++c)
#pragma unroll
    for (int r = 0; r < 4; ++r) {
      int bb = q * 4 + r;
      int j  = jb + c * 16;
      int ad = bb * 256 + ((((j >> 3) ^ (bb & 7))) << 3) + (j & 7);
      hl[0][ad] = f2bs(h[c][r]);
    }

  // gx prefetch for t=0 (rows 4q..4q+3 at col g, 8B coalesced)
  const unsigned short* g0 = GX + ((size_t)wg * 768 + jb) * 16 + q * 4;
  ushort4 pf[6];
  pf[0] = *(const ushort4*)(g0);                // gate0, c=0
  pf[1] = *(const ushort4*)(g0 + 256);          // gate0, c=1
  pf[2] = *(const ushort4*)(g0 + 4096);         // gate1, c=0
  pf[3] = *(const ushort4*)(g0 + 4096 + 256);   // gate1, c=1
  pf[4] = *(const ushort4*)(g0 + 8192);         // gate2, c=0
  pf[5] = *(const ushort4*)(g0 + 8192 + 256);   // gate2, c=1

  float* yp = Y + (size_t)(b0 + q * 4) * 256 + jb;
  __syncthreads();

  for (int t = 0; t < Tc; ++t) {
    // ---- gh = bf16(h) @ W_hh^T  (A from LDS, B resident in VGPRs) ----
    f32x4 acc[6];
#pragma unroll
    for (int i = 0; i < 6; ++i) acc[i] = f32x4{0.f, 0.f, 0.f, 0.f};
    const unsigned short* hb = hl[t & 1];
#pragma unroll
    for (int kt = 0; kt < 8; ++kt) {
      int ad = m * 256 + (((kt * 4 + q) ^ (m & 7)) << 3);
      bf16x8 af = *(const bf16x8*)(hb + ad);
#pragma unroll
      for (int i = 0; i < 6; ++i)
        acc[i] = __builtin_amdgcn_mfma_f32_16x16x32_bf16(af, bw[i][kt], acc[i], 0, 0, 0);
    }

    // ---- pointwise GRU cell (f32), write next-h to other LDS buffer ----
    unsigned short* hw = hl[(t + 1) & 1];
#pragma unroll
    for (int c = 0; c < 2; ++c) {
      ushort4 pr4 = pf[c];          // i_r (+b_ih+b_hh)
      ushort4 pz4 = pf[2 + c];      // i_z (+b_ih+b_hh)
      ushort4 pn4 = pf[4 + c];      // i_n (+b_ih)
#pragma unroll
      for (int r = 0; r < 4; ++r) {
        unsigned short pru = (r == 0) ? pr4.x : (r == 1) ? pr4.y : (r == 2) ? pr4.z : pr4.w;
        unsigned short pzu = (r == 0) ? pz4.x : (r == 1) ? pz4.y : (r == 2) ? pz4.z : pz4.w;
        unsigned short pnu = (r == 0) ? pn4.x : (r == 1) ? pn4.y : (r == 2) ? pn4.z : pn4.w;
        float ir  = b2f(pru);
        float iz  = b2f(pzu);
        float inn = b2f(pnu);
        float rr = 1.f / (1.f + __expf(-(ir + acc[c][r])));
        float zz = 1.f / (1.f + __expf(-(iz + acc[2 + c][r])));
        float nx = inn + rr * (acc[4 + c][r] + bhn[c]);
        float e2 = __expf(2.f * nx);
        float nn = 1.f - 2.f / (e2 + 1.f);      // tanh(nx)
        float hv = nn + zz * (h[c][r] - nn);    // (1-z)*n + z*h
        h[c][r] = hv;
        int bb = q * 4 + r;
        int j  = jb + c * 16;
        int ad = bb * 256 + ((((j >> 3) ^ (bb & 7))) << 3) + (j & 7);
        hw[ad] = f2bs(hv);
        yp[r * 256 + c * 16] = hv;
      }
    }

    // ---- prefetch gx(t+1) into pf (lands during next MFMA phase) ----
    if (t + 1 < Tc) {
      g0 += 196608;                              // 16*768*16 elems per step
      pf[0] = *(const ushort4*)(g0);
      pf[1] = *(const ushort4*)(g0 + 256);
      pf[2] = *(const ushort4*)(g0 + 4096);
      pf[3] = *(const ushort4*)(g0 + 4096 + 256);
      pf[4] = *(const ushort4*)(g0 + 8192);
      pf[5] = *(const ushort4*)(g0 + 8192 + 256);
    }
    yp += 65536;
    __syncthreads();
  }

  // carry out (f32) or finals (f32)
#pragma unroll
  for (int c = 0; c < 2; ++c)
#pragma unroll
    for (int r = 0; r < 4; ++r) {
      int bb = b0 + q * 4 + r;
      int j  = jb + c * 16;
      if (FIN) FIN[bb * 256 + j] = h[c][r];
      else     hcar[bb * 256 + j] = h[c][r];
    }
}

// ---------------------------------------------------------------------------
extern "C" void kernel_launch(void* const* d_in, const int* in_sizes, int n_in,
                              void* d_out, int out_size, void* d_ws, size_t ws_size,
                              hipStream_t stream) {
  const float* x    = (const float*)d_in[0]; // [512][256][128]
  const float* h0   = (const float*)d_in[1]; // [6][256][256]
  const float* Wih0 = (const float*)d_in[2]; // [768][128]
  const float* Wih  = (const float*)d_in[3]; // [5][768][256]
  const float* Whh  = (const float*)d_in[4]; // [6][768][256]
  const float* bih  = (const float*)d_in[5]; // [6][768]
  const float* bhh  = (const float*)d_in[6]; // [6][768]
  float* out = (float*)d_out;

  // largest Tc (<=32) whose ws fits NLAY gx buffers + NLAY carries.
  // gx per layer = Tc*16*768*16*2 B = Tc*393216 B; hcar per layer = 256KB.
  int Tc = 32;
  while (Tc > 4) {
    size_t need = (size_t)NLAY * Tc * 393216ull + (size_t)NLAY * 262144ull;
    if (need <= ws_size) break;
    Tc >>= 1;
  }
  const int nch = 512 / Tc;
  const size_t gxElems = (size_t)Tc * 196608;   // ushorts per layer buffer

  char* ws = (char*)d_ws;
  unsigned short* gx0   = (unsigned short*)ws;
  float*          hcar0 = (float*)(ws + (size_t)NLAY * Tc * 393216ull);

  float* cur = out;                              // [512][256][256] f32
  float* fin = out + (size_t)512 * 256 * 256;    // [6][256][256] f32

  const int nslots = NLAY + nch - 1;
  for (int s = 0; s < nslots; ++s) {
    int lmin = s - (nch - 1); if (lmin < 0) lmin = 0;
    int lmax = (s < NLAY - 1) ? s : (NLAY - 1);

    GemmBatch gb = {};
    ScanBatch sb = {};
    int np = 0;
    for (int l = lmin; l <= lmax; ++l, ++np) {
      int c = s - l;
      gb.X[np]   = (l == 0) ? (x + (size_t)c * Tc * 256 * 128)
                            : (cur + (size_t)c * Tc * 65536);
      gb.W[np]   = (l == 0) ? Wih0 : (Wih + (size_t)(l - 1) * 768 * 256);
      gb.bih[np] = bih + l * 768;
      gb.bhh[np] = bhh + l * 768;
      gb.GX[np]  = gx0 + (size_t)l * gxElems;
      gb.K[np]   = (l == 0) ? 128 : 256;

      sb.GX[np]    = gb.GX[np];
      sb.Whh[np]   = Whh + (size_t)l * 768 * 256;
      sb.bhh[np]   = bhh + l * 768;
      sb.hcar[np]  = hcar0 + (size_t)l * 65536;
      sb.h0[np]    = h0 + (size_t)l * 65536;
      sb.Y[np]     = cur + (size_t)c * Tc * 65536;
      sb.FIN[np]   = (c == nch - 1) ? (fin + (size_t)l * 65536) : (float*)nullptr;
      sb.first[np] = (c == 0) ? 1 : 0;
    }
    sb.Tc = Tc;

    gx_gemm<<<dim3(Tc * 2, 6, np), dim3(256), 0, stream>>>(gb);
    gru_scan<<<dim3(16, np), dim3(512), 0, stream>>>(sb);
  }
  (void)in_sizes; (void)n_in; (void)out_size; (void)ws_size;
}

// Round 2
// 2603.467 us; speedup vs baseline: 5.5800x; 1.8060x over previous
//
#include <hip/hip_runtime.h>

// 6-layer GRU, T=512, B=256, I=128, H=256. ALL I/O IS FLOAT32. MFMA operands
// are converted f32->bf16 on the fly; h carried in f32; internal gx ws is bf16.
// d_out = [cur 512*256*256][finals 6*256*256] f32.
//
// Wavefront pipeline across (layer, chunk): per slot s launch ONE batched
// gx_gemm (blockIdx.z = pair) then ONE batched gru_scan (blockIdx.y = pair).
// Single-stream ordering supplies every dependency.
//
// SCAN v3 (this round): the old "weight-stationary" bw[6][8] (192 VGPR) was
// silently SPILLED under __launch_bounds__(512,2)'s 128-reg cap -> 384KB of
// scratch reloads per WG per step = the whole 6us step time. Now:
//  - __launch_bounds__(512,1): 256-VGPR budget (only 96 WGs exist; occupancy
//    beyond 1 WG/CU is useless for this latency-chain kernel).
//  - gates r,z weights resident in VGPRs (bw[4][8] = 128 regs); gate n weights
//    staged ONCE into LDS (128KB, fragment-contiguous per lane, ds_read_b128
//    conflict-free per step). 144KB dynamic LDS total.
//  - gx prefetch double-buffered (pfA/pfB), issued at TOP of step t for t+1.
//  - per-step barrier = "s_waitcnt lgkmcnt(0); s_barrier" ONLY: vmcnt stays
//    outstanding across the barrier (Y stores + gx prefetch off the chain).
//  - v_rcp_f32 via __builtin_amdgcn_rcpf for sigmoid/tanh.

#define NLAY 6

typedef __bf16 bf16x8 __attribute__((ext_vector_type(8)));
typedef float  f32x4  __attribute__((ext_vector_type(4)));

typedef const unsigned int __attribute__((address_space(1)))* gp1_t;
typedef unsigned int __attribute__((address_space(3)))* lp3_t;

__device__ __forceinline__ float b2f(unsigned short u) {
  union { unsigned int i; float f; } v; v.i = ((unsigned int)u) << 16; return v.f;
}
__device__ __forceinline__ unsigned short f2bs(float f) {
  union { __bf16 b; unsigned short s; } v; v.b = (__bf16)f; return v.s;
}
__device__ __forceinline__ bf16x8 cvt8(f32x4 lo, f32x4 hi) {
  bf16x8 r;
#pragma unroll
  for (int i = 0; i < 4; ++i) { r[i] = (__bf16)lo[i]; r[4 + i] = (__bf16)hi[i]; }
  return r;
}

struct GemmBatch {
  const float* X[NLAY];
  const float* W[NLAY];
  const float* bih[NLAY];
  const float* bhh[NLAY];
  unsigned short* GX[NLAY];
  int K[NLAY];
};

// ---------------------------------------------------------------------------
// gx[m,g] = sum_k X[m,k]*W[g,k] + bias(g);  m = t*256+b (chunk-local t)
// X: [M][K] f32 row-major, W: [768][K] f32 row-major, K in {128,256}.
// GX (bf16): (t,b,g) -> GX[((t*16 + (b>>4))*768 + g)*16 + (b&15)]
// grid = (Tc*2, 6, npairs), block = 256. LDS slabs [128 rows][32 k] f32, 8
// 16B-groups per row; physical group g holds logical group g ^ (row&7).
// ---------------------------------------------------------------------------
__global__ __launch_bounds__(256) void gx_gemm(GemmBatch args)
{
  __shared__ __align__(16) float Asf[128 * 32];
  __shared__ __align__(16) float Bsf[128 * 32];
  const int p = blockIdx.z;
  const float* __restrict__ X  = args.X[p];
  const float* __restrict__ W  = args.W[p];
  const float* __restrict__ bihp = args.bih[p];
  const float* __restrict__ bhhp = args.bhh[p];
  unsigned short* __restrict__ GX = args.GX[p];
  const int K = args.K[p];

  const int tid  = threadIdx.x;
  const int lane = tid & 63;
  const int w    = tid >> 6;           // wave 0..3
  const int wy   = w >> 1, wx = w & 1; // 2x2 wave grid, 64x64 per wave
  const int l15  = lane & 15, q = lane >> 4;
  const int m0   = blockIdx.x * 128;
  const int n0   = blockIdx.y * 128;

  f32x4 acc[4][4];
#pragma unroll
  for (int a = 0; a < 4; ++a)
#pragma unroll
    for (int b = 0; b < 4; ++b) acc[a][b] = f32x4{0.f, 0.f, 0.f, 0.f};

  const int kiters = K >> 5;
  for (int kt = 0; kt < kiters; ++kt) {
    // stage: 1024 16B-chunks per slab (128 rows x 8 groups of 4 floats)
#pragma unroll
    for (int i = 0; i < 4; ++i) {
      int ci  = (w * 4 + i) * 64 + lane;   // 0..1023
      int row = ci >> 3;
      int g   = ci & 7;
      int kg  = g ^ (row & 7);
      const float* srcA = X + (size_t)(m0 + row) * K + kt * 32 + kg * 4;
      const float* srcB = W + (size_t)(n0 + row) * K + kt * 32 + kg * 4;
      __builtin_amdgcn_global_load_lds((gp1_t)(const void*)srcA,
          (lp3_t)(void*)((char*)Asf + (w * 4 + i) * 1024), 16, 0, 0);
      __builtin_amdgcn_global_load_lds((gp1_t)(const void*)srcB,
          (lp3_t)(void*)((char*)Bsf + (w * 4 + i) * 1024), 16, 0, 0);
    }
    __syncthreads();

    bf16x8 a[4], b[4];
#pragma unroll
    for (int tm = 0; tm < 4; ++tm) {
      int row = wy * 64 + tm * 16 + l15;
      int p0  = (2 * q) ^ (row & 7);
      int p1  = (2 * q + 1) ^ (row & 7);
      f32x4 lo = *(const f32x4*)(Asf + row * 32 + p0 * 4);
      f32x4 hi = *(const f32x4*)(Asf + row * 32 + p1 * 4);
      a[tm] = cvt8(lo, hi);
    }
#pragma unroll
    for (int tn = 0; tn < 4; ++tn) {
      int row = wx * 64 + tn * 16 + l15;
      int p0  = (2 * q) ^ (row & 7);
      int p1  = (2 * q + 1) ^ (row & 7);
      f32x4 lo = *(const f32x4*)(Bsf + row * 32 + p0 * 4);
      f32x4 hi = *(const f32x4*)(Bsf + row * 32 + p1 * 4);
      b[tn] = cvt8(lo, hi);
    }
#pragma unroll
    for (int tm = 0; tm < 4; ++tm)
#pragma unroll
      for (int tn = 0; tn < 4; ++tn)
        acc[tm][tn] = __builtin_amdgcn_mfma_f32_16x16x32_bf16(a[tm], b[tn], acc[tm][tn], 0, 0, 0);
    __syncthreads();
  }

  // epilogue: bias add (+b_hh folded for gates r,z i.e. g<512), bf16, permuted
#pragma unroll
  for (int tn = 0; tn < 4; ++tn) {
    int g = n0 + wx * 64 + tn * 16 + l15;
    float bias = bihp[g] + (g < 512 ? bhhp[g] : 0.f);
#pragma unroll
    for (int tm = 0; tm < 4; ++tm) {
#pragma unroll
      for (int r = 0; r < 4; ++r) {
        int m = m0 + wy * 64 + tm * 16 + q * 4 + r;  // C row = 4*q + r
        int t = m >> 8, bb = m & 255;
        size_t dst = ((size_t)(t * 16 + (bb >> 4)) * 768 + g) * 16 + (bb & 15);
        GX[dst] = f2bs(acc[tm][tn][r] + bias);
      }
    }
  }
}

struct ScanBatch {
  const unsigned short* GX[NLAY];
  const float* Whh[NLAY];
  const float* bhh[NLAY];
  float* hcar[NLAY];
  const float* h0[NLAY];
  float* Y[NLAY];
  float* FIN[NLAY];
  int first[NLAY];
  int Tc;
};

// per-step: prefetch gx(t+1) into PN at top (latency hidden under MFMA+cell),
// MFMA over 8 k-tiles (r,z B-frags from VGPR, n B-frags from LDS), pointwise
// cell consuming PC, ds_write next-h, then lgkm-only barrier (vmcnt open).
#define GRU_STEP(T, PC, PN)                                                   \
  {                                                                           \
    if ((T) + 1 < Tc) {                                                       \
      PN[0] = *(const ushort4*)(gpf);                                         \
      PN[1] = *(const ushort4*)(gpf + 256);                                   \
      PN[2] = *(const ushort4*)(gpf + 4096);                                  \
      PN[3] = *(const ushort4*)(gpf + 4096 + 256);                            \
      PN[4] = *(const ushort4*)(gpf + 8192);                                  \
      PN[5] = *(const ushort4*)(gpf + 8192 + 256);                            \
      gpf += 196608;                                                          \
    }                                                                         \
    f32x4 acc[6];                                                             \
    _Pragma("unroll")                                                         \
    for (int i = 0; i < 6; ++i) acc[i] = f32x4{0.f, 0.f, 0.f, 0.f};           \
    {                                                                         \
      const unsigned short* hb = hl + ((T) & 1) * 4096;                       \
      _Pragma("unroll")                                                       \
      for (int kt = 0; kt < 8; ++kt) {                                        \
        int ad = m * 256 + (((kt * 4 + q) ^ (m & 7)) << 3);                   \
        bf16x8 af = *(const bf16x8*)(hb + ad);                                \
        bf16x8 b4 = *(const bf16x8*)(wnl + kt * 512);                         \
        bf16x8 b5 = *(const bf16x8*)(wnl + 4096 + kt * 512);                  \
        acc[0] = __builtin_amdgcn_mfma_f32_16x16x32_bf16(af, bw[0][kt], acc[0], 0, 0, 0); \
        acc[1] = __builtin_amdgcn_mfma_f32_16x16x32_bf16(af, bw[1][kt], acc[1], 0, 0, 0); \
        acc[2] = __builtin_amdgcn_mfma_f32_16x16x32_bf16(af, bw[2][kt], acc[2], 0, 0, 0); \
        acc[3] = __builtin_amdgcn_mfma_f32_16x16x32_bf16(af, bw[3][kt], acc[3], 0, 0, 0); \
        acc[4] = __builtin_amdgcn_mfma_f32_16x16x32_bf16(af, b4, acc[4], 0, 0, 0); \
        acc[5] = __builtin_amdgcn_mfma_f32_16x16x32_bf16(af, b5, acc[5], 0, 0, 0); \
      }                                                                       \
    }                                                                         \
    {                                                                         \
      unsigned short* hw = hl + (((T) + 1) & 1) * 4096;                       \
      _Pragma("unroll")                                                       \
      for (int c = 0; c < 2; ++c) {                                           \
        ushort4 pr4 = PC[c];                                                  \
        ushort4 pz4 = PC[2 + c];                                              \
        ushort4 pn4 = PC[4 + c];                                              \
        _Pragma("unroll")                                                     \
        for (int r = 0; r < 4; ++r) {                                         \
          unsigned short pru = (r == 0) ? pr4.x : (r == 1) ? pr4.y : (r == 2) ? pr4.z : pr4.w; \
          unsigned short pzu = (r == 0) ? pz4.x : (r == 1) ? pz4.y : (r == 2) ? pz4.z : pz4.w; \
          unsigned short pnu = (r == 0) ? pn4.x : (r == 1) ? pn4.y : (r == 2) ? pn4.z : pn4.w; \
          float ir  = b2f(pru);                                               \
          float iz  = b2f(pzu);                                               \
          float inn = b2f(pnu);                                               \
          float rr = __builtin_amdgcn_rcpf(1.f + __expf(-(ir + acc[c][r])));  \
          float zz = __builtin_amdgcn_rcpf(1.f + __expf(-(iz + acc[2 + c][r]))); \
          float nx = inn + rr * (acc[4 + c][r] + bhn[c]);                     \
          float e2 = __expf(2.f * nx);                                        \
          float nn = 1.f - 2.f * __builtin_amdgcn_rcpf(e2 + 1.f);             \
          float hv = nn + zz * (h[c][r] - nn);                                \
          h[c][r] = hv;                                                       \
          int bb = q * 4 + r;                                                 \
          int j  = jb + c * 16;                                               \
          int ad = bb * 256 + ((((j >> 3) ^ (bb & 7))) << 3) + (j & 7);       \
          hw[ad] = f2bs(hv);                                                  \
          yp[r * 256 + c * 16] = hv;                                          \
        }                                                                     \
      }                                                                       \
    }                                                                         \
    yp += 65536;                                                              \
    asm volatile("s_waitcnt lgkmcnt(0)\n\ts_barrier" ::: "memory");           \
  }

// ---------------------------------------------------------------------------
// Recurrent scan. grid = (16, npairs). 8 waves; wave w owns gh columns
// [32w,32w+32) for all 3 gates. r,z W_hh bf16 B-fragments resident in VGPRs
// (128 regs); n-gate B-fragments in LDS (128KB, per-lane contiguous). h in f32
// regs; bf16 h in double-buffered swizzled LDS (A-op). Dynamic LDS 144KB.
// ---------------------------------------------------------------------------
__global__ __launch_bounds__(512, 1) void gru_scan(ScanBatch args)
{
  extern __shared__ __align__(16) char smem[];
  unsigned short* hl = (unsigned short*)smem;              // 2 x 16x256 bf16 (16KB)
  unsigned short* wn = (unsigned short*)(smem + 16384);    // [16 tile][8 kt][64 lane][8] (128KB)

  const int p = blockIdx.y;
  const unsigned short* __restrict__ GX = args.GX[p];
  const float* __restrict__ Whh = args.Whh[p];
  const float* __restrict__ bhh = args.bhh[p];
  float* __restrict__ hcar = args.hcar[p];
  const float* __restrict__ h0 = args.h0[p];
  float* __restrict__ Y = args.Y[p];
  float* __restrict__ FIN = args.FIN[p];
  const int Tc = args.Tc;
  const int first = args.first[p];

  const int wg  = blockIdx.x;
  const int b0  = wg << 4;
  const int tid = threadIdx.x;
  const int lane = tid & 63;
  const int w  = tid >> 6;       // 0..7
  const int m  = lane & 15;
  const int q  = lane >> 4;
  const int jb = w * 32 + m;     // j col base (c adds 16)

  // resident W_hh B-fragments for gates r,z: B[k][n], n=l15 row, k = kt*32+8q+i
  bf16x8 bw[4][8];
#pragma unroll
  for (int gate = 0; gate < 2; ++gate)
#pragma unroll
    for (int c = 0; c < 2; ++c) {
      int n = gate * 256 + jb + c * 16;
#pragma unroll
      for (int kt = 0; kt < 8; ++kt) {
        f32x4 lo = *(const f32x4*)(Whh + (size_t)n * 256 + kt * 32 + q * 8);
        f32x4 hi = *(const f32x4*)(Whh + (size_t)n * 256 + kt * 32 + q * 8 + 4);
        bw[gate * 2 + c][kt] = cvt8(lo, hi);
      }
    }

  // n-gate W_hh fragments -> LDS, per-lane contiguous (each lane writes then
  // re-reads exactly its own fragment; ds_read_b128 conflict-free).
#pragma unroll
  for (int c = 0; c < 2; ++c) {
    int n = 512 + jb + c * 16;
#pragma unroll
    for (int kt = 0; kt < 8; ++kt) {
      f32x4 lo = *(const f32x4*)(Whh + (size_t)n * 256 + kt * 32 + q * 8);
      f32x4 hi = *(const f32x4*)(Whh + (size_t)n * 256 + kt * 32 + q * 8 + 4);
      *(bf16x8*)(wn + (((size_t)(w * 2 + c) * 8 + kt) * 64 + lane) * 8) = cvt8(lo, hi);
    }
  }
  const unsigned short* wnl = wn + ((size_t)(w * 2) * 8 * 64 + lane) * 8;

  float bhn[2];
#pragma unroll
  for (int c = 0; c < 2; ++c) bhn[c] = bhh[512 + jb + c * 16];

  // h registers: rows b0+4q+r, cols jb+16c
  float h[2][4];
#pragma unroll
  for (int c = 0; c < 2; ++c)
#pragma unroll
    for (int r = 0; r < 4; ++r) {
      int bb = b0 + q * 4 + r;
      int j  = jb + c * 16;
      h[c][r] = first ? h0[bb * 256 + j] : hcar[bb * 256 + j];
    }

  // init LDS h buf 0 (swizzle: addr = b*256 + (((j>>3)^(b&7))<<3) + (j&7))
#pragma unroll
  for (int c = 0; c < 2; ++c)
#pragma unroll
    for (int r = 0; r < 4; ++r) {
      int bb = q * 4 + r;
      int j  = jb + c * 16;
      int ad = bb * 256 + ((((j >> 3) ^ (bb & 7))) << 3) + (j & 7);
      hl[ad] = f2bs(h[c][r]);
    }

  // gx prefetch for t=0 (rows 4q..4q+3 at col g, 8B coalesced)
  const unsigned short* gpf = GX + ((size_t)wg * 768 + jb) * 16 + q * 4;
  ushort4 pfA[6], pfB[6];
  pfA[0] = *(const ushort4*)(gpf);
  pfA[1] = *(const ushort4*)(gpf + 256);
  pfA[2] = *(const ushort4*)(gpf + 4096);
  pfA[3] = *(const ushort4*)(gpf + 4096 + 256);
  pfA[4] = *(const ushort4*)(gpf + 8192);
  pfA[5] = *(const ushort4*)(gpf + 8192 + 256);
  gpf += 196608;

  float* yp = Y + (size_t)(b0 + q * 4) * 256 + jb;
  __syncthreads();

  for (int t = 0; t < Tc; t += 2) {
    GRU_STEP(t, pfA, pfB);
    GRU_STEP(t + 1, pfB, pfA);
  }

  // carry out (f32) or finals (f32)
#pragma unroll
  for (int c = 0; c < 2; ++c)
#pragma unroll
    for (int r = 0; r < 4; ++r) {
      int bb = b0 + q * 4 + r;
      int j  = jb + c * 16;
      if (FIN) FIN[bb * 256 + j] = h[c][r];
      else     hcar[bb * 256 + j] = h[c][r];
    }
}

// ---------------------------------------------------------------------------
extern "C" void kernel_launch(void* const* d_in, const int* in_sizes, int n_in,
                              void* d_out, int out_size, void* d_ws, size_t ws_size,
                              hipStream_t stream) {
  const float* x    = (const float*)d_in[0]; // [512][256][128]
  const float* h0   = (const float*)d_in[1]; // [6][256][256]
  const float* Wih0 = (const float*)d_in[2]; // [768][128]
  const float* Wih  = (const float*)d_in[3]; // [5][768][256]
  const float* Whh  = (const float*)d_in[4]; // [6][768][256]
  const float* bih  = (const float*)d_in[5]; // [6][768]
  const float* bhh  = (const float*)d_in[6]; // [6][768]
  float* out = (float*)d_out;

  static int cfg = 0;
  if (!cfg) {
    hipFuncSetAttribute((const void*)gru_scan,
                        hipFuncAttributeMaxDynamicSharedMemorySize, 147456);
    cfg = 1;
  }

  // largest Tc (<=32) whose ws fits NLAY gx buffers + NLAY carries.
  // gx per layer = Tc*16*768*16*2 B = Tc*393216 B; hcar per layer = 256KB.
  int Tc = 32;
  while (Tc > 4) {
    size_t need = (size_t)NLAY * Tc * 393216ull + (size_t)NLAY * 262144ull;
    if (need <= ws_size) break;
    Tc >>= 1;
  }
  const int nch = 512 / Tc;
  const size_t gxElems = (size_t)Tc * 196608;   // ushorts per layer buffer

  char* ws = (char*)d_ws;
  unsigned short* gx0   = (unsigned short*)ws;
  float*          hcar0 = (float*)(ws + (size_t)NLAY * Tc * 393216ull);

  float* cur = out;                              // [512][256][256] f32
  float* fin = out + (size_t)512 * 256 * 256;    // [6][256][256] f32

  const int nslots = NLAY + nch - 1;
  for (int s = 0; s < nslots; ++s) {
    int lmin = s - (nch - 1); if (lmin < 0) lmin = 0;
    int lmax = (s < NLAY - 1) ? s : (NLAY - 1);

    GemmBatch gb = {};
    ScanBatch sb = {};
    int np = 0;
    for (int l = lmin; l <= lmax; ++l, ++np) {
      int c = s - l;
      gb.X[np]   = (l == 0) ? (x + (size_t)c * Tc * 256 * 128)
                            : (cur + (size_t)c * Tc * 65536);
      gb.W[np]   = (l == 0) ? Wih0 : (Wih + (size_t)(l - 1) * 768 * 256);
      gb.bih[np] = bih + l * 768;
      gb.bhh[np] = bhh + l * 768;
      gb.GX[np]  = gx0 + (size_t)l * gxElems;
      gb.K[np]   = (l == 0) ? 128 : 256;

      sb.GX[np]    = gb.GX[np];
      sb.Whh[np]   = Whh + (size_t)l * 768 * 256;
      sb.bhh[np]   = bhh + l * 768;
      sb.hcar[np]  = hcar0 + (size_t)l * 65536;
      sb.h0[np]    = h0 + (size_t)l * 65536;
      sb.Y[np]     = cur + (size_t)c * Tc * 65536;
      sb.FIN[np]   = (c == nch - 1) ? (fin + (size_t)l * 65536) : (float*)nullptr;
      sb.first[np] = (c == 0) ? 1 : 0;
    }
    sb.Tc = Tc;

    gx_gemm<<<dim3(Tc * 2, 6, np), dim3(256), 0, stream>>>(gb);
    gru_scan<<<dim3(16, np), dim3(512), 147456, stream>>>(sb);
  }
  (void)in_sizes; (void)n_in; (void)out_size; (void)ws_size;
}

// Round 3
// 2553.305 us; speedup vs baseline: 5.6896x; 1.0196x over previous
//
#include <hip/hip_runtime.h>

// 6-layer GRU, T=512, B=256, I=128, H=256. ALL I/O IS FLOAT32. MFMA operands
// are converted f32->bf16 on the fly; h carried in f32; internal gx ws is bf16.
// d_out = [cur 512*256*256][finals 6*256*256] f32.
//
// Wavefront pipeline across (layer, chunk): per slot s launch ONE batched
// gx_gemm (blockIdx.z = pair) then ONE batched gru_scan (blockIdx.y = pair).
// Single-stream ordering supplies every dependency.
//
// SCAN v4 (this round): the step is latency/VALU-chain bound (~6870 cyc):
// pointwise ~2200 cyc, MFMA ~1400, LDS ~770, rest = dependency stalls. So:
//  - exp2 PREFOLD: gx and W_hh r,z parts pre-scaled by log2e; n parts by
//    2*log2e (gemm epilogue + weight preload). sigmoid = rcp(1+exp2(-x)),
//    tanh = 1-2*rcp(1+exp2(x')) with no runtime scaling muls. bhn folded
//    into the n-gate MFMA accumulator init. ~40% fewer pointwise VALU ops.
//  - GATE-PHASE SPLIT: kt-loop 1 computes acc[0..3] (r,z) keeping the 8
//    A-fragments in regs; kt-loop 2 issues n-gate MFMAs (acc[4,5]). The
//    sigmoid VALU only needs acc[0..3] -> scheduler overlaps it with the
//    n-MFMA drain instead of serializing.
//  - per-step barrier stays lgkmcnt-only (vmcnt open across it).

#define NLAY 6

typedef __bf16 bf16x8 __attribute__((ext_vector_type(8)));
typedef float  f32x4  __attribute__((ext_vector_type(4)));

typedef const unsigned int __attribute__((address_space(1)))* gp1_t;
typedef unsigned int __attribute__((address_space(3)))* lp3_t;

#define LOG2E  1.44269504088896340736f
#define LOG2E2 2.88539008177792681472f

__device__ __forceinline__ float b2f(unsigned short u) {
  union { unsigned int i; float f; } v; v.i = ((unsigned int)u) << 16; return v.f;
}
__device__ __forceinline__ unsigned short f2bs(float f) {
  union { __bf16 b; unsigned short s; } v; v.b = (__bf16)f; return v.s;
}
__device__ __forceinline__ bf16x8 cvt8(f32x4 lo, f32x4 hi) {
  bf16x8 r;
#pragma unroll
  for (int i = 0; i < 4; ++i) { r[i] = (__bf16)lo[i]; r[4 + i] = (__bf16)hi[i]; }
  return r;
}
__device__ __forceinline__ bf16x8 cvt8s(f32x4 lo, f32x4 hi, float s) {
  bf16x8 r;
#pragma unroll
  for (int i = 0; i < 4; ++i) { r[i] = (__bf16)(lo[i] * s); r[4 + i] = (__bf16)(hi[i] * s); }
  return r;
}

struct GemmBatch {
  const float* X[NLAY];
  const float* W[NLAY];
  const float* bih[NLAY];
  const float* bhh[NLAY];
  unsigned short* GX[NLAY];
  int K[NLAY];
};

// ---------------------------------------------------------------------------
// gx[m,g] = (sum_k X[m,k]*W[g,k] + bias(g)) * scale(g);  m = t*256+b
// scale = log2e for gates r,z (g<512), 2*log2e for gate n (exp2 prefold).
// X: [M][K] f32 row-major, W: [768][K] f32 row-major, K in {128,256}.
// GX (bf16): (t,b,g) -> GX[((t*16 + (b>>4))*768 + g)*16 + (b&15)]
// grid = (Tc*2, 6, npairs), block = 256. LDS slabs [128 rows][32 k] f32, 8
// 16B-groups per row; physical group g holds logical group g ^ (row&7).
// ---------------------------------------------------------------------------
__global__ __launch_bounds__(256) void gx_gemm(GemmBatch args)
{
  __shared__ __align__(16) float Asf[128 * 32];
  __shared__ __align__(16) float Bsf[128 * 32];
  const int p = blockIdx.z;
  const float* __restrict__ X  = args.X[p];
  const float* __restrict__ W  = args.W[p];
  const float* __restrict__ bihp = args.bih[p];
  const float* __restrict__ bhhp = args.bhh[p];
  unsigned short* __restrict__ GX = args.GX[p];
  const int K = args.K[p];

  const int tid  = threadIdx.x;
  const int lane = tid & 63;
  const int w    = tid >> 6;           // wave 0..3
  const int wy   = w >> 1, wx = w & 1; // 2x2 wave grid, 64x64 per wave
  const int l15  = lane & 15, q = lane >> 4;
  const int m0   = blockIdx.x * 128;
  const int n0   = blockIdx.y * 128;

  f32x4 acc[4][4];
#pragma unroll
  for (int a = 0; a < 4; ++a)
#pragma unroll
    for (int b = 0; b < 4; ++b) acc[a][b] = f32x4{0.f, 0.f, 0.f, 0.f};

  const int kiters = K >> 5;
  for (int kt = 0; kt < kiters; ++kt) {
    // stage: 1024 16B-chunks per slab (128 rows x 8 groups of 4 floats)
#pragma unroll
    for (int i = 0; i < 4; ++i) {
      int ci  = (w * 4 + i) * 64 + lane;   // 0..1023
      int row = ci >> 3;
      int g   = ci & 7;
      int kg  = g ^ (row & 7);
      const float* srcA = X + (size_t)(m0 + row) * K + kt * 32 + kg * 4;
      const float* srcB = W + (size_t)(n0 + row) * K + kt * 32 + kg * 4;
      __builtin_amdgcn_global_load_lds((gp1_t)(const void*)srcA,
          (lp3_t)(void*)((char*)Asf + (w * 4 + i) * 1024), 16, 0, 0);
      __builtin_amdgcn_global_load_lds((gp1_t)(const void*)srcB,
          (lp3_t)(void*)((char*)Bsf + (w * 4 + i) * 1024), 16, 0, 0);
    }
    __syncthreads();

    bf16x8 a[4], b[4];
#pragma unroll
    for (int tm = 0; tm < 4; ++tm) {
      int row = wy * 64 + tm * 16 + l15;
      int p0  = (2 * q) ^ (row & 7);
      int p1  = (2 * q + 1) ^ (row & 7);
      f32x4 lo = *(const f32x4*)(Asf + row * 32 + p0 * 4);
      f32x4 hi = *(const f32x4*)(Asf + row * 32 + p1 * 4);
      a[tm] = cvt8(lo, hi);
    }
#pragma unroll
    for (int tn = 0; tn < 4; ++tn) {
      int row = wx * 64 + tn * 16 + l15;
      int p0  = (2 * q) ^ (row & 7);
      int p1  = (2 * q + 1) ^ (row & 7);
      f32x4 lo = *(const f32x4*)(Bsf + row * 32 + p0 * 4);
      f32x4 hi = *(const f32x4*)(Bsf + row * 32 + p1 * 4);
      b[tn] = cvt8(lo, hi);
    }
#pragma unroll
    for (int tm = 0; tm < 4; ++tm)
#pragma unroll
      for (int tn = 0; tn < 4; ++tn)
        acc[tm][tn] = __builtin_amdgcn_mfma_f32_16x16x32_bf16(a[tm], b[tn], acc[tm][tn], 0, 0, 0);
    __syncthreads();
  }

  // epilogue: bias add (+b_hh folded for r,z), exp2-prefold scale, bf16, permuted
#pragma unroll
  for (int tn = 0; tn < 4; ++tn) {
    int g = n0 + wx * 64 + tn * 16 + l15;
    float bias = bihp[g] + (g < 512 ? bhhp[g] : 0.f);
    float scl  = (g < 512) ? LOG2E : LOG2E2;
#pragma unroll
    for (int tm = 0; tm < 4; ++tm) {
#pragma unroll
      for (int r = 0; r < 4; ++r) {
        int m = m0 + wy * 64 + tm * 16 + q * 4 + r;  // C row = 4*q + r
        int t = m >> 8, bb = m & 255;
        size_t dst = ((size_t)(t * 16 + (bb >> 4)) * 768 + g) * 16 + (bb & 15);
        GX[dst] = f2bs((acc[tm][tn][r] + bias) * scl);
      }
    }
  }
}

struct ScanBatch {
  const unsigned short* GX[NLAY];
  const float* Whh[NLAY];
  const float* bhh[NLAY];
  float* hcar[NLAY];
  const float* h0[NLAY];
  float* Y[NLAY];
  float* FIN[NLAY];
  int first[NLAY];
  int Tc;
};

// per-step: prefetch gx(t+1) into PN at top (latency hidden under MFMA+cell);
// kt-loop 1: A-frags from LDS (kept in regs) + r,z MFMAs (acc[0..3], VGPR B);
// kt-loop 2: n-gate MFMAs (acc[4,5], LDS B) -- overlaps with sigmoid VALU;
// pointwise cell (exp2-prefolded), ds_write next-h, lgkm-only barrier.
#define GRU_STEP(T, PC, PN)                                                   \
  {                                                                           \
    if ((T) + 1 < Tc) {                                                       \
      PN[0] = *(const ushort4*)(gpf);                                         \
      PN[1] = *(const ushort4*)(gpf + 256);                                   \
      PN[2] = *(const ushort4*)(gpf + 4096);                                  \
      PN[3] = *(const ushort4*)(gpf + 4096 + 256);                            \
      PN[4] = *(const ushort4*)(gpf + 8192);                                  \
      PN[5] = *(const ushort4*)(gpf + 8192 + 256);                            \
      gpf += 196608;                                                          \
    }                                                                         \
    f32x4 acc[6];                                                             \
    _Pragma("unroll")                                                         \
    for (int i = 0; i < 4; ++i) acc[i] = f32x4{0.f, 0.f, 0.f, 0.f};           \
    acc[4] = f32x4{bhn[0], bhn[0], bhn[0], bhn[0]};                           \
    acc[5] = f32x4{bhn[1], bhn[1], bhn[1], bhn[1]};                           \
    bf16x8 af[8];                                                             \
    {                                                                         \
      const unsigned short* hb = hl + ((T) & 1) * 4096;                       \
      _Pragma("unroll")                                                       \
      for (int kt = 0; kt < 8; ++kt) {                                        \
        int ad = m * 256 + (((kt * 4 + q) ^ (m & 7)) << 3);                   \
        af[kt] = *(const bf16x8*)(hb + ad);                                   \
        acc[0] = __builtin_amdgcn_mfma_f32_16x16x32_bf16(af[kt], bw[0][kt], acc[0], 0, 0, 0); \
        acc[1] = __builtin_amdgcn_mfma_f32_16x16x32_bf16(af[kt], bw[1][kt], acc[1], 0, 0, 0); \
        acc[2] = __builtin_amdgcn_mfma_f32_16x16x32_bf16(af[kt], bw[2][kt], acc[2], 0, 0, 0); \
        acc[3] = __builtin_amdgcn_mfma_f32_16x16x32_bf16(af[kt], bw[3][kt], acc[3], 0, 0, 0); \
      }                                                                       \
      _Pragma("unroll")                                                       \
      for (int kt = 0; kt < 8; ++kt) {                                        \
        bf16x8 b4 = *(const bf16x8*)(wnl + kt * 512);                         \
        bf16x8 b5 = *(const bf16x8*)(wnl + 4096 + kt * 512);                  \
        acc[4] = __builtin_amdgcn_mfma_f32_16x16x32_bf16(af[kt], b4, acc[4], 0, 0, 0); \
        acc[5] = __builtin_amdgcn_mfma_f32_16x16x32_bf16(af[kt], b5, acc[5], 0, 0, 0); \
      }                                                                       \
    }                                                                         \
    {                                                                         \
      unsigned short* hw = hl + (((T) + 1) & 1) * 4096;                       \
      _Pragma("unroll")                                                       \
      for (int c = 0; c < 2; ++c) {                                           \
        ushort4 pr4 = PC[c];                                                  \
        ushort4 pz4 = PC[2 + c];                                              \
        ushort4 pn4 = PC[4 + c];                                              \
        _Pragma("unroll")                                                     \
        for (int r = 0; r < 4; ++r) {                                         \
          unsigned short pru = (r == 0) ? pr4.x : (r == 1) ? pr4.y : (r == 2) ? pr4.z : pr4.w; \
          unsigned short pzu = (r == 0) ? pz4.x : (r == 1) ? pz4.y : (r == 2) ? pz4.z : pz4.w; \
          unsigned short pnu = (r == 0) ? pn4.x : (r == 1) ? pn4.y : (r == 2) ? pn4.z : pn4.w; \
          float ir  = b2f(pru);   /* log2e * (i_r + b) */                     \
          float iz  = b2f(pzu);   /* log2e * (i_z + b) */                     \
          float inn = b2f(pnu);   /* 2log2e * (i_n + b_ih) */                 \
          float xr = ir + acc[c][r];                                          \
          float rr = __builtin_amdgcn_rcpf(1.f + __builtin_amdgcn_exp2f(-xr)); \
          float xz = iz + acc[2 + c][r];                                      \
          float zz = __builtin_amdgcn_rcpf(1.f + __builtin_amdgcn_exp2f(-xz)); \
          float nx = __builtin_fmaf(rr, acc[4 + c][r], inn);                  \
          float e2 = __builtin_amdgcn_exp2f(nx);                              \
          float nn = __builtin_fmaf(-2.f, __builtin_amdgcn_rcpf(1.f + e2), 1.f); \
          float hv = __builtin_fmaf(zz, h[c][r] - nn, nn);                    \
          h[c][r] = hv;                                                       \
          int bb = q * 4 + r;                                                 \
          int j  = jb + c * 16;                                               \
          int ad = bb * 256 + ((((j >> 3) ^ (bb & 7))) << 3) + (j & 7);       \
          hw[ad] = f2bs(hv);                                                  \
          yp[r * 256 + c * 16] = hv;                                          \
        }                                                                     \
      }                                                                       \
    }                                                                         \
    yp += 65536;                                                              \
    asm volatile("s_waitcnt lgkmcnt(0)\n\ts_barrier" ::: "memory");           \
  }

// ---------------------------------------------------------------------------
// Recurrent scan. grid = (16, npairs). 8 waves; wave w owns gh columns
// [32w,32w+32) for all 3 gates. r,z W_hh bf16 B-fragments (pre-scaled log2e)
// resident in VGPRs (128 regs); n-gate B-fragments (pre-scaled 2log2e) in LDS
// (128KB, per-lane contiguous). h in f32 regs; bf16 h in double-buffered
// swizzled LDS (A-op). Dynamic LDS 144KB.
// ---------------------------------------------------------------------------
__global__ __launch_bounds__(512, 1) void gru_scan(ScanBatch args)
{
  extern __shared__ __align__(16) char smem[];
  unsigned short* hl = (unsigned short*)smem;              // 2 x 16x256 bf16 (16KB)
  unsigned short* wn = (unsigned short*)(smem + 16384);    // [16 tile][8 kt][64 lane][8] (128KB)

  const int p = blockIdx.y;
  const unsigned short* __restrict__ GX = args.GX[p];
  const float* __restrict__ Whh = args.Whh[p];
  const float* __restrict__ bhh = args.bhh[p];
  float* __restrict__ hcar = args.hcar[p];
  const float* __restrict__ h0 = args.h0[p];
  float* __restrict__ Y = args.Y[p];
  float* __restrict__ FIN = args.FIN[p];
  const int Tc = args.Tc;
  const int first = args.first[p];

  const int wg  = blockIdx.x;
  const int b0  = wg << 4;
  const int tid = threadIdx.x;
  const int lane = tid & 63;
  const int w  = tid >> 6;       // 0..7
  const int m  = lane & 15;
  const int q  = lane >> 4;
  const int jb = w * 32 + m;     // j col base (c adds 16)

  // resident W_hh B-fragments for gates r,z (pre-scaled by log2e):
  // B[k][n], n=l15 row, k = kt*32+8q+i
  bf16x8 bw[4][8];
#pragma unroll
  for (int gate = 0; gate < 2; ++gate)
#pragma unroll
    for (int c = 0; c < 2; ++c) {
      int n = gate * 256 + jb + c * 16;
#pragma unroll
      for (int kt = 0; kt < 8; ++kt) {
        f32x4 lo = *(const f32x4*)(Whh + (size_t)n * 256 + kt * 32 + q * 8);
        f32x4 hi = *(const f32x4*)(Whh + (size_t)n * 256 + kt * 32 + q * 8 + 4);
        bw[gate * 2 + c][kt] = cvt8s(lo, hi, LOG2E);
      }
    }

  // n-gate W_hh fragments (pre-scaled by 2log2e) -> LDS, per-lane contiguous.
#pragma unroll
  for (int c = 0; c < 2; ++c) {
    int n = 512 + jb + c * 16;
#pragma unroll
    for (int kt = 0; kt < 8; ++kt) {
      f32x4 lo = *(const f32x4*)(Whh + (size_t)n * 256 + kt * 32 + q * 8);
      f32x4 hi = *(const f32x4*)(Whh + (size_t)n * 256 + kt * 32 + q * 8 + 4);
      *(bf16x8*)(wn + (((size_t)(w * 2 + c) * 8 + kt) * 64 + lane) * 8) = cvt8s(lo, hi, LOG2E2);
    }
  }
  const unsigned short* wnl = wn + ((size_t)(w * 2) * 8 * 64 + lane) * 8;

  float bhn[2];   // pre-scaled by 2log2e; folded into acc[4,5] init
#pragma unroll
  for (int c = 0; c < 2; ++c) bhn[c] = bhh[512 + jb + c * 16] * LOG2E2;

  // h registers: rows b0+4q+r, cols jb+16c
  float h[2][4];
#pragma unroll
  for (int c = 0; c < 2; ++c)
#pragma unroll
    for (int r = 0; r < 4; ++r) {
      int bb = b0 + q * 4 + r;
      int j  = jb + c * 16;
      h[c][r] = first ? h0[bb * 256 + j] : hcar[bb * 256 + j];
    }

  // init LDS h buf 0 (swizzle: addr = b*256 + (((j>>3)^(b&7))<<3) + (j&7))
#pragma unroll
  for (int c = 0; c < 2; ++c)
#pragma unroll
    for (int r = 0; r < 4; ++r) {
      int bb = q * 4 + r;
      int j  = jb + c * 16;
      int ad = bb * 256 + ((((j >> 3) ^ (bb & 7))) << 3) + (j & 7);
      hl[ad] = f2bs(h[c][r]);
    }

  // gx prefetch for t=0 (rows 4q..4q+3 at col g, 8B coalesced)
  const unsigned short* gpf = GX + ((size_t)wg * 768 + jb) * 16 + q * 4;
  ushort4 pfA[6], pfB[6];
  pfA[0] = *(const ushort4*)(gpf);
  pfA[1] = *(const ushort4*)(gpf + 256);
  pfA[2] = *(const ushort4*)(gpf + 4096);
  pfA[3] = *(const ushort4*)(gpf + 4096 + 256);
  pfA[4] = *(const ushort4*)(gpf + 8192);
  pfA[5] = *(const ushort4*)(gpf + 8192 + 256);
  gpf += 196608;

  float* yp = Y + (size_t)(b0 + q * 4) * 256 + jb;
  __syncthreads();

  for (int t = 0; t < Tc; t += 2) {
    GRU_STEP(t, pfA, pfB);
    GRU_STEP(t + 1, pfB, pfA);
  }

  // carry out (f32) or finals (f32)
#pragma unroll
  for (int c = 0; c < 2; ++c)
#pragma unroll
    for (int r = 0; r < 4; ++r) {
      int bb = b0 + q * 4 + r;
      int j  = jb + c * 16;
      if (FIN) FIN[bb * 256 + j] = h[c][r];
      else     hcar[bb * 256 + j] = h[c][r];
    }
}

// ---------------------------------------------------------------------------
extern "C" void kernel_launch(void* const* d_in, const int* in_sizes, int n_in,
                              void* d_out, int out_size, void* d_ws, size_t ws_size,
                              hipStream_t stream) {
  const float* x    = (const float*)d_in[0]; // [512][256][128]
  const float* h0   = (const float*)d_in[1]; // [6][256][256]
  const float* Wih0 = (const float*)d_in[2]; // [768][128]
  const float* Wih  = (const float*)d_in[3]; // [5][768][256]
  const float* Whh  = (const float*)d_in[4]; // [6][768][256]
  const float* bih  = (const float*)d_in[5]; // [6][768]
  const float* bhh  = (const float*)d_in[6]; // [6][768]
  float* out = (float*)d_out;

  static int cfg = 0;
  if (!cfg) {
    hipFuncSetAttribute((const void*)gru_scan,
                        hipFuncAttributeMaxDynamicSharedMemorySize, 147456);
    cfg = 1;
  }

  // largest Tc (<=32) whose ws fits NLAY gx buffers + NLAY carries.
  // gx per layer = Tc*16*768*16*2 B = Tc*393216 B; hcar per layer = 256KB.
  int Tc = 32;
  while (Tc > 4) {
    size_t need = (size_t)NLAY * Tc * 393216ull + (size_t)NLAY * 262144ull;
    if (need <= ws_size) break;
    Tc >>= 1;
  }
  const int nch = 512 / Tc;
  const size_t gxElems = (size_t)Tc * 196608;   // ushorts per layer buffer

  char* ws = (char*)d_ws;
  unsigned short* gx0   = (unsigned short*)ws;
  float*          hcar0 = (float*)(ws + (size_t)NLAY * Tc * 393216ull);

  float* cur = out;                              // [512][256][256] f32
  float* fin = out + (size_t)512 * 256 * 256;    // [6][256][256] f32

  const int nslots = NLAY + nch - 1;
  for (int s = 0; s < nslots; ++s) {
    int lmin = s - (nch - 1); if (lmin < 0) lmin = 0;
    int lmax = (s < NLAY - 1) ? s : (NLAY - 1);

    GemmBatch gb = {};
    ScanBatch sb = {};
    int np = 0;
    for (int l = lmin; l <= lmax; ++l, ++np) {
      int c = s - l;
      gb.X[np]   = (l == 0) ? (x + (size_t)c * Tc * 256 * 128)
                            : (cur + (size_t)c * Tc * 65536);
      gb.W[np]   = (l == 0) ? Wih0 : (Wih + (size_t)(l - 1) * 768 * 256);
      gb.bih[np] = bih + l * 768;
      gb.bhh[np] = bhh + l * 768;
      gb.GX[np]  = gx0 + (size_t)l * gxElems;
      gb.K[np]   = (l == 0) ? 128 : 256;

      sb.GX[np]    = gb.GX[np];
      sb.Whh[np]   = Whh + (size_t)l * 768 * 256;
      sb.bhh[np]   = bhh + l * 768;
      sb.hcar[np]  = hcar0 + (size_t)l * 65536;
      sb.h0[np]    = h0 + (size_t)l * 65536;
      sb.Y[np]     = cur + (size_t)c * Tc * 65536;
      sb.FIN[np]   = (c == nch - 1) ? (fin + (size_t)l * 65536) : (float*)nullptr;
      sb.first[np] = (c == 0) ? 1 : 0;
    }
    sb.Tc = Tc;

    gx_gemm<<<dim3(Tc * 2, 6, np), dim3(256), 0, stream>>>(gb);
    gru_scan<<<dim3(16, np), dim3(512), 147456, stream>>>(sb);
  }
  (void)in_sizes; (void)n_in; (void)out_size; (void)ws_size;
}